// Round 18
// baseline (592.926 us; speedup 1.0000x reference)
//
#include <hip/hip_runtime.h>
#include <hip/hip_bf16.h>
#include <stdint.h>

#define TOK 8192
#define NQ 2048
#define DIMX 1024
#define CTXD 768

typedef __attribute__((ext_vector_type(8))) short short8;
typedef __attribute__((ext_vector_type(4))) float f32x4;
typedef __attribute__((ext_vector_type(2))) unsigned int u32x2;

typedef __attribute__((address_space(3))) uint32_t lds_u32_t;
typedef const __attribute__((address_space(1))) uint32_t glb_u32_t;

__device__ __forceinline__ void gld_lds16(const void* g, void* l) {
  __builtin_amdgcn_global_load_lds((glb_u32_t*)g, (lds_u32_t*)l, 16, 0, 0);
}

__device__ __forceinline__ uint16_t f2bf(float f) {
  union { float f; uint32_t u; } v; v.f = f;
  uint32_t r = v.u + 0x7fffu + ((v.u >> 16) & 1u);
  return (uint16_t)(r >> 16);
}

__device__ __forceinline__ uint32_t cvt_pk_bf16(float lo, float hi) {
  uint32_t d;
  asm("v_cvt_pk_bf16_f32 %0, %1, %2" : "=v"(d) : "v"(lo), "v"(hi));
  return d;
}

// Fast exp2 via compiler builtin (hazard-safe v_exp_f32 scheduling).
// NOTE: bare inline-asm v_exp_f32 (no trans-op wait state) was the r5-r7
// corruption source -- never reintroduce it.
__device__ __forceinline__ float fexp2(float x) {
#if __has_builtin(__builtin_amdgcn_exp2f)
  return __builtin_amdgcn_exp2f(x);
#else
  float d;
  asm volatile("v_exp_f32 %0, %1\n\ts_nop 1" : "=v"(d) : "v"(x));
  return d;
#endif
}

// ---- LayerNorm (both tensors) + 4x weight transpose, ONE launch ----------
__global__ __launch_bounds__(256)
void ln_tr_kernel(const float* __restrict__ x, const float* __restrict__ gx,
                  const float* __restrict__ bx,
                  const float* __restrict__ c, const float* __restrict__ gc,
                  const float* __restrict__ bc,
                  uint16_t* __restrict__ xn, uint16_t* __restrict__ cn,
                  const float* __restrict__ W0, const float* __restrict__ W1,
                  const float* __restrict__ W2, const float* __restrict__ W3,
                  uint16_t* __restrict__ T0, uint16_t* __restrict__ T1,
                  uint16_t* __restrict__ T2, uint16_t* __restrict__ T3) {
  int bid = blockIdx.x;
  int tid = threadIdx.x;
  if (bid >= 2 * TOK) {
    int t = bid - 2 * TOK;
    int z = t >> 10, rem = t & 1023;
    const float* W = (z == 0) ? W0 : (z == 1) ? W1 : (z == 2) ? W2 : W3;
    uint16_t* WT   = (z == 0) ? T0 : (z == 1) ? T1 : (z == 2) ? T2 : T3;
    int K = (z == 1 || z == 2) ? CTXD : DIMX;
    const int N = DIMX;
    int c0 = (rem & 31) * 32, r0 = (rem >> 5) * 32;
    if (r0 >= K) return;
    __shared__ float tb[32][33];
    int tx = tid & 31, ty = tid >> 5;
#pragma unroll
    for (int i = 0; i < 4; i++)
      tb[ty + 8*i][tx] = W[(size_t)(r0 + ty + 8*i) * N + c0 + tx];
    __syncthreads();
#pragma unroll
    for (int i = 0; i < 4; i++)
      WT[(size_t)(c0 + ty + 8*i) * K + r0 + tx] = f2bf(tb[tx][ty + 8*i]);
    return;
  }
  int row = bid;
  const float *src, *g, *bb; uint16_t* dst; int COLS;
  if (row < TOK) { src = x; g = gx; bb = bx; dst = xn; COLS = DIMX; }
  else { row -= TOK; src = c; g = gc; bb = bc; dst = cn; COLS = CTXD; }
  bool act = tid * 4 < COLS;
  float4 v = make_float4(0.f, 0.f, 0.f, 0.f);
  if (act) v = *(const float4*)(src + (size_t)row * COLS + tid * 4);
  float s1 = v.x + v.y + v.z + v.w;
  float s2 = v.x*v.x + v.y*v.y + v.z*v.z + v.w*v.w;
#pragma unroll
  for (int off = 1; off < 64; off <<= 1) {
    s1 += __shfl_xor(s1, off);
    s2 += __shfl_xor(s2, off);
  }
  __shared__ float sm[2][4];
  int w = tid >> 6;
  if ((tid & 63) == 0) { sm[0][w] = s1; sm[1][w] = s2; }
  __syncthreads();
  float t1 = sm[0][0] + sm[0][1] + sm[0][2] + sm[0][3];
  float t2 = sm[1][0] + sm[1][1] + sm[1][2] + sm[1][3];
  float mu = t1 / COLS;
  float var = t2 / COLS - mu * mu;
  float rs = rsqrtf(var + 1e-5f);
  if (act) {
    float4 gv = *(const float4*)(g + tid * 4);
    float4 bv = *(const float4*)(bb + tid * 4);
    uint32_t lo = (uint32_t)f2bf((v.x - mu) * rs * gv.x + bv.x) |
                  ((uint32_t)f2bf((v.y - mu) * rs * gv.y + bv.y) << 16);
    uint32_t hi = (uint32_t)f2bf((v.z - mu) * rs * gv.z + bv.z) |
                  ((uint32_t)f2bf((v.w - mu) * rs * gv.w + bv.w) << 16);
    uint2 o; o.x = lo; o.y = hi;
    *(uint2*)(dst + (size_t)row * COLS + tid * 4) = o;
  }
}

// ------------- shared GEMM block body (128x128 tile, BK=64) --------------
// PERMC epilogue: VT cols stored kappa'-permuted within each 64-group so the
// attention PV contraction slot (kk,g,j) holds key (kk*2+j2)*16+g*4+(j&3).
__device__ __forceinline__ void gemm_block(
    const uint16_t* __restrict__ A, const uint16_t* __restrict__ BT,
    void* __restrict__ C, int N, int K, float oscale,
    int out_bf16, int permc, int m0, int n0,
    uint16_t* Al, uint16_t* Bl, int tid) {
  int l = tid & 63, w = tid >> 6;
  int g = l >> 4, r = l & 15;
  int wm = w >> 1, wn = w & 1;
  f32x4 acc[4][4] = {};
  int srow = tid >> 3, sslot = tid & 7;

  for (int kt = 0; kt < K; kt += 64) {
    __syncthreads();
#pragma unroll
    for (int c = 0; c < 4; c++) {
      int row = c * 32 + srow;
      int ksrc = (sslot * 8) ^ ((row & 7) << 3);
      gld_lds16(A + (size_t)(m0 + row) * K + kt + ksrc, Al + (c * 256 + w * 64) * 8);
    }
#pragma unroll
    for (int c = 0; c < 4; c++) {
      int row = c * 32 + srow;
      int ksrc = (sslot * 8) ^ ((row & 7) << 3);
      gld_lds16(BT + (size_t)(n0 + row) * K + kt + ksrc, Bl + (c * 256 + w * 64) * 8);
    }
    __syncthreads();
#pragma unroll
    for (int kk = 0; kk < 2; kk++) {
      int kb2 = (kk * 32 + g * 8) * 2;
      short8 af[4], bfr[4];
#pragma unroll
      for (int mf = 0; mf < 4; mf++) {
        int row = wm * 64 + mf * 16 + r;
        af[mf] = *(const short8*)((const char*)Al + row * 128 + (kb2 ^ ((row & 7) << 4)));
      }
#pragma unroll
      for (int nf = 0; nf < 4; nf++) {
        int row = wn * 64 + nf * 16 + r;
        bfr[nf] = *(const short8*)((const char*)Bl + row * 128 + (kb2 ^ ((row & 7) << 4)));
      }
#pragma unroll
      for (int mf = 0; mf < 4; mf++)
#pragma unroll
        for (int nf = 0; nf < 4; nf++)
          acc[mf][nf] = __builtin_amdgcn_mfma_f32_16x16x32_bf16(af[mf], bfr[nf], acc[mf][nf], 0, 0, 0);
    }
  }
#pragma unroll
  for (int mf = 0; mf < 4; mf++) {
#pragma unroll
    for (int i = 0; i < 4; i++) {
      size_t row = (size_t)m0 + wm * 64 + mf * 16 + g * 4 + i;
      if (permc) {
        int pbase = ((r >> 3) << 4) | (((r >> 2) & 1) << 3) | (r & 3);
        uint16_t* cb = (uint16_t*)C + row * N + n0 + wn * 64;
        cb[pbase +  0] = f2bf(acc[mf][0][i]);
        cb[pbase +  4] = f2bf(acc[mf][1][i]);
        cb[pbase + 32] = f2bf(acc[mf][2][i]);
        cb[pbase + 36] = f2bf(acc[mf][3][i]);
      } else {
#pragma unroll
        for (int nf = 0; nf < 4; nf++) {
          int col = n0 + wn * 64 + nf * 16 + r;
          float val = acc[mf][nf][i] * oscale;
          if (out_bf16) ((uint16_t*)C)[row * N + col] = f2bf(val);
          else          ((float*)C)[row * N + col] = val;
        }
      }
    }
  }
}

// -------- merged Q/K/VT projection GEMMs: one 1536-block launch ---------
__global__ __launch_bounds__(256)
void gemm_proj3_kernel(const uint16_t* __restrict__ xn, const uint16_t* __restrict__ cn,
                       const uint16_t* __restrict__ WqT, const uint16_t* __restrict__ WkT,
                       const uint16_t* __restrict__ WvT,
                       uint16_t* __restrict__ Qs, uint16_t* __restrict__ Ks,
                       uint16_t* __restrict__ VTs, float qscale) {
  __shared__ __align__(16) uint16_t Al[128 * 64];
  __shared__ __align__(16) uint16_t Bl[128 * 64];
  int flat = blockIdx.x;
  flat = (flat & 7) * 192 + (flat >> 3);   // bijective XCD chunk remap
  const uint16_t* A; const uint16_t* BT; uint16_t* C;
  int N, K, permc, m0, n0;
  float osc = 1.f;
  if (flat < 512) {
    A = xn; BT = WqT; C = Qs; N = DIMX; K = DIMX; permc = 0; osc = qscale;
    n0 = (flat & 7) * 128; m0 = (flat >> 3) * 128;
  } else if (flat < 1024) {
    int f = flat - 512;
    A = cn; BT = WkT; C = Ks; N = DIMX; K = CTXD; permc = 0;
    n0 = (f & 7) * 128; m0 = (f >> 3) * 128;
  } else {
    int f = flat - 1024;
    A = WvT; BT = cn; C = VTs; N = TOK; K = CTXD; permc = 1;
    n0 = (f & 63) * 128; m0 = (f >> 6) * 128;
  }
  gemm_block(A, BT, C, N, K, osc, 1, permc, m0, n0, Al, Bl, threadIdx.x);
}

// ---------------- O projection (fp32 out), 128x128 (r12-proven) ----------
__global__ __launch_bounds__(256)
void gemm_out_kernel(const uint16_t* __restrict__ A, const uint16_t* __restrict__ BT,
                     float* __restrict__ C, int M, int N, int K) {
  __shared__ __align__(16) uint16_t Al[128 * 64];
  __shared__ __align__(16) uint16_t Bl[128 * 64];
  int flat = blockIdx.y * gridDim.x + blockIdx.x;
  int nwg = gridDim.x * gridDim.y;
  flat = (flat & 7) * (nwg >> 3) + (flat >> 3);
  int bx = flat & (gridDim.x - 1);
  int by = flat / gridDim.x;
  gemm_block(A, BT, C, N, K, 1.f, 0, 0, by * 128, bx * 128, Al, Bl, threadIdx.x);
}

// ------- Flash cross-attention (swapped QK^T, qb=4, 2-wave blocks) -------
// r16-proven per-wave compute (in-register P, kappa'-matched V, setprio,
// single-buffer 2-__syncthreads staging) with 2 WAVES PER BLOCK (128 thr,
// QBLK=128, grid 1024): 4 independent blocks/CU instead of 2 -> phase
// serialization hidden by cross-block overlap; barrier scope halves.
// Staging: each wave issues 4 K + 4 V gld_lds16 covering 8-row groups
// (linear LDS dest = wave-uniform base + lane*16; swizzle on global src).
// LDS 16 KB, pure K/V.
__global__ __launch_bounds__(128, 4)
void attn_kernel(const uint16_t* __restrict__ Q, const uint16_t* __restrict__ Kp,
                 const uint16_t* __restrict__ VT, uint16_t* __restrict__ O) {
  __shared__ __align__(16) uint16_t Kl[64 * 64];        // [key][d] swizzled
  __shared__ __align__(16) uint16_t Vl[64 * 64];        // [d][slot] swizzled
  int tid = threadIdx.x;
  int l = tid & 63, w = tid >> 6;                       // w in {0,1}
  int g = l >> 4, r = l & 15;
  // grid (16,64) = 1024 blocks; XCD chunk: 128 consecutive new-ids
  // (= 8 complete bh) per XCD.
  int flat = blockIdx.y * 16 + blockIdx.x;
  flat = (flat & 7) * 128 + (flat >> 3);
  int q0 = (flat & 15) * 128;
  int bh = flat >> 4, b = bh >> 4, h = bh & 15;

  short8 qa[4][2];
#pragma unroll
  for (int qb = 0; qb < 4; qb++) {
    const uint16_t* qptr = Q + (size_t)(b * NQ + q0 + w * 64 + qb * 16 + r) * DIMX + h * 64;
    qa[qb][0] = *(const short8*)(qptr + g * 8);
    qa[qb][1] = *(const short8*)(qptr + 32 + g * 8);
  }

  float lpart[4] = {0.f, 0.f, 0.f, 0.f};
  f32x4 oacc[4][4] = {};

  const uint16_t* kbase = Kp + (size_t)(b * NQ) * DIMX + h * 64;
  const uint16_t* vbase = VT + (size_t)(h * 64) * TOK + b * NQ;
  int lrow = l >> 3;                                    // 0..7
  int koff = ((l & 7) * 8) ^ (lrow << 3);               // swizzled src offset

  for (int kv0 = 0; kv0 < NQ; kv0 += 64) {
    __syncthreads();
#pragma unroll
    for (int j = 0; j < 4; j++) {
      int rg = w * 4 + j;                               // 8-row group 0..7
      int row = rg * 8 + lrow;
      gld_lds16(kbase + (size_t)(kv0 + row) * DIMX + koff, Kl + rg * 512);
      gld_lds16(vbase + (size_t)row * TOK + kv0 + koff, Vl + rg * 512);
    }
    __syncthreads();

    // S^T = K Q^T: lane (g,r) gets S[q=r (+qb*16)][key = c*16 + g*4 + i]
    f32x4 sc[4][4] = {};
    __builtin_amdgcn_s_setprio(1);
#pragma unroll
    for (int kk = 0; kk < 2; kk++) {
      int kb2 = (kk * 32 + g * 8) * 2;
#pragma unroll
      for (int c = 0; c < 4; c++) {
        int row = c * 16 + r;
        short8 kf = *(const short8*)((const char*)Kl + row * 128 + (kb2 ^ ((row & 7) << 4)));
#pragma unroll
        for (int qb = 0; qb < 4; qb++)
          sc[qb][c] = __builtin_amdgcn_mfma_f32_16x16x32_bf16(kf, qa[qb][kk], sc[qb][c], 0, 0, 0);
      }
    }
    __builtin_amdgcn_s_setprio(0);

    // p = exp2(S), packed in-register into PV A-fragments:
    // pa[qb][kk] element j = P[q=r][key (kk*2+(j>>2))*16 + g*4 + (j&3)]
    short8 pa[4][2];
#pragma unroll
    for (int qb = 0; qb < 4; qb++) {
      float pe[4][4];
#pragma unroll
      for (int c = 0; c < 4; c++)
#pragma unroll
        for (int i = 0; i < 4; i++) {
          pe[c][i] = fexp2(sc[qb][c][i]);
          lpart[qb] += pe[c][i];
        }
#pragma unroll
      for (int kk = 0; kk < 2; kk++) {
        union { uint32_t u[4]; short8 s; } pk;
        pk.u[0] = cvt_pk_bf16(pe[kk * 2][0], pe[kk * 2][1]);
        pk.u[1] = cvt_pk_bf16(pe[kk * 2][2], pe[kk * 2][3]);
        pk.u[2] = cvt_pk_bf16(pe[kk * 2 + 1][0], pe[kk * 2 + 1][1]);
        pk.u[3] = cvt_pk_bf16(pe[kk * 2 + 1][2], pe[kk * 2 + 1][3]);
        pa[qb][kk] = pk.s;
      }
    }

    // O += P V (V slots kappa'-matched to pa); vf shared across 4 qb
    __builtin_amdgcn_s_setprio(1);
#pragma unroll
    for (int kk = 0; kk < 2; kk++) {
#pragma unroll
      for (int c = 0; c < 4; c++) {
        int row = c * 16 + r;
        short8 vf = *(const short8*)((const char*)Vl + row * 128 + (((kk * 32 + g * 8) * 2) ^ ((row & 7) << 4)));
#pragma unroll
        for (int qb = 0; qb < 4; qb++)
          oacc[qb][c] = __builtin_amdgcn_mfma_f32_16x16x32_bf16(pa[qb][kk], vf, oacc[qb][c], 0, 0, 0);
      }
    }
    __builtin_amdgcn_s_setprio(0);
  }

  // lane (g,r) holds partial row-sum for q=r over its 16 keys; sum over g
#pragma unroll
  for (int qb = 0; qb < 4; qb++) {
    lpart[qb] += __shfl_xor(lpart[qb], 16);
    lpart[qb] += __shfl_xor(lpart[qb], 32);
  }

#pragma unroll
  for (int qb = 0; qb < 4; qb++) {
    uint16_t* obase = O + (size_t)(b * NQ + q0 + w * 64 + qb * 16) * DIMX + h * 64;
#pragma unroll
    for (int i = 0; i < 4; i++) {
      float li = __shfl(lpart[qb], g * 4 + i);   // l for q-row g*4+i
      float inv = 1.f / li;
#pragma unroll
      for (int c = 0; c < 4; c++)
        obase[(size_t)(g * 4 + i) * DIMX + c * 16 + r] = f2bf(oacc[qb][c][i] * inv);
    }
  }
}

// ---------------- host ----------------
extern "C" void kernel_launch(void* const* d_in, const int* in_sizes, int n_in,
                              void* d_out, int out_size, void* d_ws, size_t ws_size,
                              hipStream_t stream) {
  (void)in_sizes; (void)n_in; (void)out_size; (void)ws_size;
  const float* x       = (const float*)d_in[0];
  const float* ctx     = (const float*)d_in[1];
  const float* norm_g  = (const float*)d_in[2];
  const float* norm_b  = (const float*)d_in[3];
  const float* normc_g = (const float*)d_in[4];
  const float* normc_b = (const float*)d_in[5];
  const float* Wq      = (const float*)d_in[6];
  const float* Wk      = (const float*)d_in[7];
  const float* Wv      = (const float*)d_in[8];
  const float* Wo      = (const float*)d_in[9];

  char* p = (char*)d_ws;
  uint16_t* xn  = (uint16_t*)p; p += (size_t)TOK * DIMX * 2;
  uint16_t* cn  = (uint16_t*)p; p += (size_t)TOK * CTXD * 2;
  uint16_t* WqT = (uint16_t*)p; p += (size_t)DIMX * DIMX * 2;
  uint16_t* WkT = (uint16_t*)p; p += (size_t)DIMX * CTXD * 2;
  uint16_t* WvT = (uint16_t*)p; p += (size_t)DIMX * CTXD * 2;
  uint16_t* WoT = (uint16_t*)p; p += (size_t)DIMX * DIMX * 2;
  uint16_t* Qs  = (uint16_t*)p; p += (size_t)TOK * DIMX * 2;
  uint16_t* Ks  = (uint16_t*)p; p += (size_t)TOK * DIMX * 2;
  uint16_t* VTs = (uint16_t*)p; p += (size_t)DIMX * TOK * 2;
  uint16_t* AO  = (uint16_t*)p; p += (size_t)TOK * DIMX * 2;

  // LayerNorms + weight transposes, one launch
  ln_tr_kernel<<<2 * TOK + 4096, 256, 0, stream>>>(
      x, norm_g, norm_b, ctx, normc_g, normc_b, xn, cn,
      Wq, Wk, Wv, Wo, WqT, WkT, WvT, WoT);

  // Merged Q/K/VT projections (Q pre-scaled by 0.125*log2e for exp2 softmax)
  const float qscale = 0.125f * 1.44269504088896340736f;
  gemm_proj3_kernel<<<1536, 256, 0, stream>>>(xn, cn, WqT, WkT, WvT, Qs, Ks, VTs, qscale);

  // Flash attention (swapped QK^T, qb=4, 2-wave blocks, QBLK=128)
  attn_kernel<<<dim3(16, 64), 128, 0, stream>>>(Qs, Ks, VTs, AO);

  // Output projection (fp32 out)
  gemm_out_kernel<<<dim3(DIMX/128, TOK/128), 256, 0, stream>>>(AO, WoT, (float*)d_out, TOK, DIMX, DIMX);
}

// Round 19
// 177.762 us; speedup vs baseline: 3.3355x; 3.3355x over previous
//
#include <hip/hip_runtime.h>
#include <hip/hip_bf16.h>
#include <stdint.h>

#define TOK 8192
#define NQ 2048
#define DIMX 1024
#define CTXD 768

typedef __attribute__((ext_vector_type(8))) short short8;
typedef __attribute__((ext_vector_type(4))) float f32x4;
typedef __attribute__((ext_vector_type(2))) unsigned int u32x2;

typedef __attribute__((address_space(3))) uint32_t lds_u32_t;
typedef const __attribute__((address_space(1))) uint32_t glb_u32_t;

__device__ __forceinline__ void gld_lds16(const void* g, void* l) {
  __builtin_amdgcn_global_load_lds((glb_u32_t*)g, (lds_u32_t*)l, 16, 0, 0);
}

__device__ __forceinline__ uint16_t f2bf(float f) {
  union { float f; uint32_t u; } v; v.f = f;
  uint32_t r = v.u + 0x7fffu + ((v.u >> 16) & 1u);
  return (uint16_t)(r >> 16);
}

__device__ __forceinline__ uint32_t cvt_pk_bf16(float lo, float hi) {
  uint32_t d;
  asm("v_cvt_pk_bf16_f32 %0, %1, %2" : "=v"(d) : "v"(lo), "v"(hi));
  return d;
}

// Fast exp2 via compiler builtin (hazard-safe v_exp_f32 scheduling).
// NOTE: bare inline-asm v_exp_f32 (no trans-op wait state) was the r5-r7
// corruption source -- never reintroduce it.
__device__ __forceinline__ float fexp2(float x) {
#if __has_builtin(__builtin_amdgcn_exp2f)
  return __builtin_amdgcn_exp2f(x);
#else
  float d;
  asm volatile("v_exp_f32 %0, %1\n\ts_nop 1" : "=v"(d) : "v"(x));
  return d;
#endif
}

// ---- LayerNorm (both tensors) + 4x weight transpose, ONE launch ----------
__global__ __launch_bounds__(256)
void ln_tr_kernel(const float* __restrict__ x, const float* __restrict__ gx,
                  const float* __restrict__ bx,
                  const float* __restrict__ c, const float* __restrict__ gc,
                  const float* __restrict__ bc,
                  uint16_t* __restrict__ xn, uint16_t* __restrict__ cn,
                  const float* __restrict__ W0, const float* __restrict__ W1,
                  const float* __restrict__ W2, const float* __restrict__ W3,
                  uint16_t* __restrict__ T0, uint16_t* __restrict__ T1,
                  uint16_t* __restrict__ T2, uint16_t* __restrict__ T3) {
  int bid = blockIdx.x;
  int tid = threadIdx.x;
  if (bid >= 2 * TOK) {
    int t = bid - 2 * TOK;
    int z = t >> 10, rem = t & 1023;
    const float* W = (z == 0) ? W0 : (z == 1) ? W1 : (z == 2) ? W2 : W3;
    uint16_t* WT   = (z == 0) ? T0 : (z == 1) ? T1 : (z == 2) ? T2 : T3;
    int K = (z == 1 || z == 2) ? CTXD : DIMX;
    const int N = DIMX;
    int c0 = (rem & 31) * 32, r0 = (rem >> 5) * 32;
    if (r0 >= K) return;
    __shared__ float tb[32][33];
    int tx = tid & 31, ty = tid >> 5;
#pragma unroll
    for (int i = 0; i < 4; i++)
      tb[ty + 8*i][tx] = W[(size_t)(r0 + ty + 8*i) * N + c0 + tx];
    __syncthreads();
#pragma unroll
    for (int i = 0; i < 4; i++)
      WT[(size_t)(c0 + ty + 8*i) * K + r0 + tx] = f2bf(tb[tx][ty + 8*i]);
    return;
  }
  int row = bid;
  const float *src, *g, *bb; uint16_t* dst; int COLS;
  if (row < TOK) { src = x; g = gx; bb = bx; dst = xn; COLS = DIMX; }
  else { row -= TOK; src = c; g = gc; bb = bc; dst = cn; COLS = CTXD; }
  bool act = tid * 4 < COLS;
  float4 v = make_float4(0.f, 0.f, 0.f, 0.f);
  if (act) v = *(const float4*)(src + (size_t)row * COLS + tid * 4);
  float s1 = v.x + v.y + v.z + v.w;
  float s2 = v.x*v.x + v.y*v.y + v.z*v.z + v.w*v.w;
#pragma unroll
  for (int off = 1; off < 64; off <<= 1) {
    s1 += __shfl_xor(s1, off);
    s2 += __shfl_xor(s2, off);
  }
  __shared__ float sm[2][4];
  int w = tid >> 6;
  if ((tid & 63) == 0) { sm[0][w] = s1; sm[1][w] = s2; }
  __syncthreads();
  float t1 = sm[0][0] + sm[0][1] + sm[0][2] + sm[0][3];
  float t2 = sm[1][0] + sm[1][1] + sm[1][2] + sm[1][3];
  float mu = t1 / COLS;
  float var = t2 / COLS - mu * mu;
  float rs = rsqrtf(var + 1e-5f);
  if (act) {
    float4 gv = *(const float4*)(g + tid * 4);
    float4 bv = *(const float4*)(bb + tid * 4);
    uint32_t lo = (uint32_t)f2bf((v.x - mu) * rs * gv.x + bv.x) |
                  ((uint32_t)f2bf((v.y - mu) * rs * gv.y + bv.y) << 16);
    uint32_t hi = (uint32_t)f2bf((v.z - mu) * rs * gv.z + bv.z) |
                  ((uint32_t)f2bf((v.w - mu) * rs * gv.w + bv.w) << 16);
    uint2 o; o.x = lo; o.y = hi;
    *(uint2*)(dst + (size_t)row * COLS + tid * 4) = o;
  }
}

// ------------- shared GEMM block body (128x128 tile, BK=64) --------------
// PERMC epilogue: VT cols stored kappa'-permuted within each 64-group so the
// attention PV contraction slot (kk,g,j) holds key (kk*2+j2)*16+g*4+(j&3).
__device__ __forceinline__ void gemm_block(
    const uint16_t* __restrict__ A, const uint16_t* __restrict__ BT,
    void* __restrict__ C, int N, int K, float oscale,
    int out_bf16, int permc, int m0, int n0,
    uint16_t* Al, uint16_t* Bl, int tid) {
  int l = tid & 63, w = tid >> 6;
  int g = l >> 4, r = l & 15;
  int wm = w >> 1, wn = w & 1;
  f32x4 acc[4][4] = {};
  int srow = tid >> 3, sslot = tid & 7;

  for (int kt = 0; kt < K; kt += 64) {
    __syncthreads();
#pragma unroll
    for (int c = 0; c < 4; c++) {
      int row = c * 32 + srow;
      int ksrc = (sslot * 8) ^ ((row & 7) << 3);
      gld_lds16(A + (size_t)(m0 + row) * K + kt + ksrc, Al + (c * 256 + w * 64) * 8);
    }
#pragma unroll
    for (int c = 0; c < 4; c++) {
      int row = c * 32 + srow;
      int ksrc = (sslot * 8) ^ ((row & 7) << 3);
      gld_lds16(BT + (size_t)(n0 + row) * K + kt + ksrc, Bl + (c * 256 + w * 64) * 8);
    }
    __syncthreads();
#pragma unroll
    for (int kk = 0; kk < 2; kk++) {
      int kb2 = (kk * 32 + g * 8) * 2;
      short8 af[4], bfr[4];
#pragma unroll
      for (int mf = 0; mf < 4; mf++) {
        int row = wm * 64 + mf * 16 + r;
        af[mf] = *(const short8*)((const char*)Al + row * 128 + (kb2 ^ ((row & 7) << 4)));
      }
#pragma unroll
      for (int nf = 0; nf < 4; nf++) {
        int row = wn * 64 + nf * 16 + r;
        bfr[nf] = *(const short8*)((const char*)Bl + row * 128 + (kb2 ^ ((row & 7) << 4)));
      }
#pragma unroll
      for (int mf = 0; mf < 4; mf++)
#pragma unroll
        for (int nf = 0; nf < 4; nf++)
          acc[mf][nf] = __builtin_amdgcn_mfma_f32_16x16x32_bf16(af[mf], bfr[nf], acc[mf][nf], 0, 0, 0);
    }
  }
#pragma unroll
  for (int mf = 0; mf < 4; mf++) {
#pragma unroll
    for (int i = 0; i < 4; i++) {
      size_t row = (size_t)m0 + wm * 64 + mf * 16 + g * 4 + i;
      if (permc) {
        int pbase = ((r >> 3) << 4) | (((r >> 2) & 1) << 3) | (r & 3);
        uint16_t* cb = (uint16_t*)C + row * N + n0 + wn * 64;
        cb[pbase +  0] = f2bf(acc[mf][0][i]);
        cb[pbase +  4] = f2bf(acc[mf][1][i]);
        cb[pbase + 32] = f2bf(acc[mf][2][i]);
        cb[pbase + 36] = f2bf(acc[mf][3][i]);
      } else {
#pragma unroll
        for (int nf = 0; nf < 4; nf++) {
          int col = n0 + wn * 64 + nf * 16 + r;
          float val = acc[mf][nf][i] * oscale;
          if (out_bf16) ((uint16_t*)C)[row * N + col] = f2bf(val);
          else          ((float*)C)[row * N + col] = val;
        }
      }
    }
  }
}

// -------- merged Q/K/VT projection GEMMs: one 1536-block launch ---------
__global__ __launch_bounds__(256)
void gemm_proj3_kernel(const uint16_t* __restrict__ xn, const uint16_t* __restrict__ cn,
                       const uint16_t* __restrict__ WqT, const uint16_t* __restrict__ WkT,
                       const uint16_t* __restrict__ WvT,
                       uint16_t* __restrict__ Qs, uint16_t* __restrict__ Ks,
                       uint16_t* __restrict__ VTs, float qscale) {
  __shared__ __align__(16) uint16_t Al[128 * 64];
  __shared__ __align__(16) uint16_t Bl[128 * 64];
  int flat = blockIdx.x;
  flat = (flat & 7) * 192 + (flat >> 3);   // bijective XCD chunk remap
  const uint16_t* A; const uint16_t* BT; uint16_t* C;
  int N, K, permc, m0, n0;
  float osc = 1.f;
  if (flat < 512) {
    A = xn; BT = WqT; C = Qs; N = DIMX; K = DIMX; permc = 0; osc = qscale;
    n0 = (flat & 7) * 128; m0 = (flat >> 3) * 128;
  } else if (flat < 1024) {
    int f = flat - 512;
    A = cn; BT = WkT; C = Ks; N = DIMX; K = CTXD; permc = 0;
    n0 = (f & 7) * 128; m0 = (f >> 3) * 128;
  } else {
    int f = flat - 1024;
    A = WvT; BT = cn; C = VTs; N = TOK; K = CTXD; permc = 1;
    n0 = (f & 63) * 128; m0 = (f >> 6) * 128;
  }
  gemm_block(A, BT, C, N, K, osc, 1, permc, m0, n0, Al, Bl, threadIdx.x);
}

// ---------------- O projection (fp32 out), 128x128 (r12-proven) ----------
__global__ __launch_bounds__(256)
void gemm_out_kernel(const uint16_t* __restrict__ A, const uint16_t* __restrict__ BT,
                     float* __restrict__ C, int M, int N, int K) {
  __shared__ __align__(16) uint16_t Al[128 * 64];
  __shared__ __align__(16) uint16_t Bl[128 * 64];
  int flat = blockIdx.y * gridDim.x + blockIdx.x;
  int nwg = gridDim.x * gridDim.y;
  flat = (flat & 7) * (nwg >> 3) + (flat >> 3);
  int bx = flat & (gridDim.x - 1);
  int by = flat / gridDim.x;
  gemm_block(A, BT, C, N, K, 1.f, 0, 0, by * 128, bx * 128, Al, Bl, threadIdx.x);
}

// ------- Flash cross-attention (swapped QK^T, no P-LDS, qb=4) ------------
// r16-PROVEN configuration (passed @77.7us attn): 4 waves x 64 q-rows each
// (QBLK=256), single-buffer gld_lds16 staging between two __syncthreads,
// 16 KB LDS (pure K/V), in-register P via swapped-operand QK^T, kappa'-
// matched V, setprio, XCD chunking, __launch_bounds__(256,2).
// r17 (dbuf, +3.7us) and r18 (2-wave blocks, VGPR cap -> spill disaster)
// both regressed -- this is the frozen optimum.
__global__ __launch_bounds__(256, 2)
void attn_kernel(const uint16_t* __restrict__ Q, const uint16_t* __restrict__ Kp,
                 const uint16_t* __restrict__ VT, uint16_t* __restrict__ O) {
  __shared__ __align__(16) uint16_t Kl[64 * 64];        // [key][d] swizzled
  __shared__ __align__(16) uint16_t Vl[64 * 64];        // [d][slot] swizzled
  int tid = threadIdx.x;
  int l = tid & 63, w = tid >> 6;
  int g = l >> 4, r = l & 15;
  int flat = blockIdx.y * 8 + blockIdx.x;
  flat = (flat & 7) * 64 + (flat >> 3);
  int q0 = (flat & 7) * 256;
  int bh = flat >> 3, b = bh >> 4, h = bh & 15;

  short8 qa[4][2];
#pragma unroll
  for (int qb = 0; qb < 4; qb++) {
    const uint16_t* qptr = Q + (size_t)(b * NQ + q0 + w * 64 + qb * 16 + r) * DIMX + h * 64;
    qa[qb][0] = *(const short8*)(qptr + g * 8);
    qa[qb][1] = *(const short8*)(qptr + 32 + g * 8);
  }

  float lpart[4] = {0.f, 0.f, 0.f, 0.f};
  f32x4 oacc[4][4] = {};

  const uint16_t* kbase = Kp + (size_t)(b * NQ) * DIMX + h * 64;
  const uint16_t* vbase = VT + (size_t)(h * 64) * TOK + b * NQ;
  int srow = tid >> 3, sslot = tid & 7;

  for (int kv0 = 0; kv0 < NQ; kv0 += 64) {
    __syncthreads();
#pragma unroll
    for (int c = 0; c < 2; c++) {
      int key = c * 32 + srow;
      int dsrc = (sslot * 8) ^ ((key & 7) << 3);
      gld_lds16(kbase + (size_t)(kv0 + key) * DIMX + dsrc, Kl + (c * 256 + w * 64) * 8);
    }
#pragma unroll
    for (int c = 0; c < 2; c++) {
      int d = c * 32 + srow;
      int ksrc = (sslot * 8) ^ ((d & 7) << 3);
      gld_lds16(vbase + (size_t)d * TOK + kv0 + ksrc, Vl + (c * 256 + w * 64) * 8);
    }
    __syncthreads();

    // S^T = K Q^T: lane (g,r) gets S[q=r (+qb*16)][key = c*16 + g*4 + i]
    f32x4 sc[4][4] = {};
    __builtin_amdgcn_s_setprio(1);
#pragma unroll
    for (int kk = 0; kk < 2; kk++) {
      int kb2 = (kk * 32 + g * 8) * 2;
#pragma unroll
      for (int c = 0; c < 4; c++) {
        int row = c * 16 + r;
        short8 kf = *(const short8*)((const char*)Kl + row * 128 + (kb2 ^ ((row & 7) << 4)));
#pragma unroll
        for (int qb = 0; qb < 4; qb++)
          sc[qb][c] = __builtin_amdgcn_mfma_f32_16x16x32_bf16(kf, qa[qb][kk], sc[qb][c], 0, 0, 0);
      }
    }
    __builtin_amdgcn_s_setprio(0);

    // p = exp2(S), packed in-register into PV A-fragments:
    // pa[qb][kk] element j = P[q=r][key (kk*2+(j>>2))*16 + g*4 + (j&3)]
    short8 pa[4][2];
#pragma unroll
    for (int qb = 0; qb < 4; qb++) {
      float pe[4][4];
#pragma unroll
      for (int c = 0; c < 4; c++)
#pragma unroll
        for (int i = 0; i < 4; i++) {
          pe[c][i] = fexp2(sc[qb][c][i]);
          lpart[qb] += pe[c][i];
        }
#pragma unroll
      for (int kk = 0; kk < 2; kk++) {
        union { uint32_t u[4]; short8 s; } pk;
        pk.u[0] = cvt_pk_bf16(pe[kk * 2][0], pe[kk * 2][1]);
        pk.u[1] = cvt_pk_bf16(pe[kk * 2][2], pe[kk * 2][3]);
        pk.u[2] = cvt_pk_bf16(pe[kk * 2 + 1][0], pe[kk * 2 + 1][1]);
        pk.u[3] = cvt_pk_bf16(pe[kk * 2 + 1][2], pe[kk * 2 + 1][3]);
        pa[qb][kk] = pk.s;
      }
    }

    // O += P V (V slots kappa'-matched to pa); vf shared across 4 qb
    __builtin_amdgcn_s_setprio(1);
#pragma unroll
    for (int kk = 0; kk < 2; kk++) {
#pragma unroll
      for (int c = 0; c < 4; c++) {
        int row = c * 16 + r;
        short8 vf = *(const short8*)((const char*)Vl + row * 128 + (((kk * 32 + g * 8) * 2) ^ ((row & 7) << 4)));
#pragma unroll
        for (int qb = 0; qb < 4; qb++)
          oacc[qb][c] = __builtin_amdgcn_mfma_f32_16x16x32_bf16(pa[qb][kk], vf, oacc[qb][c], 0, 0, 0);
      }
    }
    __builtin_amdgcn_s_setprio(0);
  }

  // lane (g,r) holds partial row-sum for q=r over its 16 keys; sum over g
#pragma unroll
  for (int qb = 0; qb < 4; qb++) {
    lpart[qb] += __shfl_xor(lpart[qb], 16);
    lpart[qb] += __shfl_xor(lpart[qb], 32);
  }

#pragma unroll
  for (int qb = 0; qb < 4; qb++) {
    uint16_t* obase = O + (size_t)(b * NQ + q0 + w * 64 + qb * 16) * DIMX + h * 64;
#pragma unroll
    for (int i = 0; i < 4; i++) {
      float li = __shfl(lpart[qb], g * 4 + i);   // l for q-row g*4+i
      float inv = 1.f / li;
#pragma unroll
      for (int c = 0; c < 4; c++)
        obase[(size_t)(g * 4 + i) * DIMX + c * 16 + r] = f2bf(oacc[qb][c][i] * inv);
    }
  }
}

// ---------------- host ----------------
extern "C" void kernel_launch(void* const* d_in, const int* in_sizes, int n_in,
                              void* d_out, int out_size, void* d_ws, size_t ws_size,
                              hipStream_t stream) {
  (void)in_sizes; (void)n_in; (void)out_size; (void)ws_size;
  const float* x       = (const float*)d_in[0];
  const float* ctx     = (const float*)d_in[1];
  const float* norm_g  = (const float*)d_in[2];
  const float* norm_b  = (const float*)d_in[3];
  const float* normc_g = (const float*)d_in[4];
  const float* normc_b = (const float*)d_in[5];
  const float* Wq      = (const float*)d_in[6];
  const float* Wk      = (const float*)d_in[7];
  const float* Wv      = (const float*)d_in[8];
  const float* Wo      = (const float*)d_in[9];

  char* p = (char*)d_ws;
  uint16_t* xn  = (uint16_t*)p; p += (size_t)TOK * DIMX * 2;
  uint16_t* cn  = (uint16_t*)p; p += (size_t)TOK * CTXD * 2;
  uint16_t* WqT = (uint16_t*)p; p += (size_t)DIMX * DIMX * 2;
  uint16_t* WkT = (uint16_t*)p; p += (size_t)DIMX * CTXD * 2;
  uint16_t* WvT = (uint16_t*)p; p += (size_t)DIMX * CTXD * 2;
  uint16_t* WoT = (uint16_t*)p; p += (size_t)DIMX * DIMX * 2;
  uint16_t* Qs  = (uint16_t*)p; p += (size_t)TOK * DIMX * 2;
  uint16_t* Ks  = (uint16_t*)p; p += (size_t)TOK * DIMX * 2;
  uint16_t* VTs = (uint16_t*)p; p += (size_t)DIMX * TOK * 2;
  uint16_t* AO  = (uint16_t*)p; p += (size_t)TOK * DIMX * 2;

  // LayerNorms + weight transposes, one launch
  ln_tr_kernel<<<2 * TOK + 4096, 256, 0, stream>>>(
      x, norm_g, norm_b, ctx, normc_g, normc_b, xn, cn,
      Wq, Wk, Wv, Wo, WqT, WkT, WvT, WoT);

  // Merged Q/K/VT projections (Q pre-scaled by 0.125*log2e for exp2 softmax)
  const float qscale = 0.125f * 1.44269504088896340736f;
  gemm_proj3_kernel<<<1536, 256, 0, stream>>>(xn, cn, WqT, WkT, WvT, Qs, Ks, VTs, qscale);

  // Flash attention (swapped QK^T, qb=4, QBLK=256)
  attn_kernel<<<dim3(8, 64), 256, 0, stream>>>(Qs, Ks, VTs, AO);

  // Output projection (fp32 out)
  gemm_out_kernel<<<dim3(DIMX/128, TOK/128), 256, 0, stream>>>(AO, WoT, (float*)d_out, TOK, DIMX, DIMX);
}